// Round 1
// baseline (205.863 us; speedup 1.0000x reference)
//
#include <hip/hip_runtime.h>
#include <hip/hip_bf16.h>
#include <math.h>

// Problem constants
#define SPAN 845            // 5 * 169 = 13*13*5 cells per channel-triple span
#define PLANE 169           // 13*13
#define NCH3 63             // 21 joints * 3 coords
#define NCHIN 64            // 63 uvd ch3 + 1 conf block
#define NUM_CLASS 45
#define NUM_SEG 5

__device__ __forceinline__ float sigmoidf_(float x) {
    return 1.0f / (1.0f + expf(-x));
}

// Kernel 1: permute + sigmoid(joint0) + per-sample argmax of conf logits.
// Grid: bs*16 blocks. Block (b, g): g in [0,16). Groups 0..14 handle ch3 = 4g..4g+3.
// Group 15 handles ch3 60..62 and the conf block (ch 63) -> argmax -> top_out.
__global__ __launch_bounds__(256) void permute_argmax_kernel(
        const float* __restrict__ in,       // (bs, 320, 13, 13) = (bs*64, 845)
        float* __restrict__ uvd_out,        // (bs, 63, 13, 13, 5) = (bs*63, 845)
        float* __restrict__ top_out)        // (bs,) float(index)
{
    const int blk = blockIdx.x;
    const int b = blk >> 4;
    const int g = blk & 15;
    const int tid = threadIdx.x;

    __shared__ float lds[4 * SPAN];
    __shared__ float wv[4];
    __shared__ int   wi[4];

    // Coalesced float4 load of 4 contiguous channel spans (16B-aligned base).
    const float4* in4 = (const float4*)in;
    const int base4 = (b * 16 + g) * SPAN;   // = (b*64 + 4g)*845/4
    float4* lds4 = (float4*)lds;
    for (int f = tid; f < SPAN; f += 256) {
        lds4[f] = in4[base4 + f];
    }
    __syncthreads();

    const int nch = (g == 15) ? 3 : 4;
    const int ch0 = g * 4;
    for (int c = 0; c < nch; ++c) {
        const int ch3 = ch0 + c;
        const bool sig = (ch3 < 3);          // joint 0 (HAND_ROOT): ch3 = 0,1,2
        const int obase = (b * NCH3 + ch3) * SPAN;
        const float* src = &lds[c * SPAN];
        for (int t = tid; t < SPAN; t += 256) {
            const int ij = t / 5;
            const int d  = t - ij * 5;
            float v = src[d * PLANE + ij];
            if (sig) v = sigmoidf_(v);
            uvd_out[obase + t] = v;
        }
    }

    if (g == 15) {
        // Argmax over conf logits (sigmoid monotonic -> raw argmax).
        // Tie-break: lowest flat index t (matches jax.lax.top_k stability).
        const float* conf = &lds[3 * SPAN];
        float bv = -INFINITY;
        int   bi = SPAN;
        for (int t = tid; t < SPAN; t += 256) {
            const int ij = t / 5;
            const int d  = t - ij * 5;
            const float v = conf[d * PLANE + ij];
            if (v > bv || (v == bv && t < bi)) { bv = v; bi = t; }
        }
        // wave (64-lane) reduce
        for (int off = 32; off > 0; off >>= 1) {
            const float ov = __shfl_down(bv, off);
            const int   oi = __shfl_down(bi, off);
            if (ov > bv || (ov == bv && oi < bi)) { bv = ov; bi = oi; }
        }
        if ((tid & 63) == 0) { wv[tid >> 6] = bv; wi[tid >> 6] = bi; }
        __syncthreads();
        if (tid == 0) {
            for (int w = 1; w < 4; ++w) {
                if (wv[w] > bv || (wv[w] == bv && wi[w] < bi)) { bv = wv[w]; bi = wi[w]; }
            }
            top_out[b] = (float)bi;
        }
    }
}

// Kernel 2: per clip (512), gather best-cell uvd for 5 segments, average, FC.
// mean over segments commutes with the linear FC layer.
__global__ __launch_bounds__(64) void fc_consensus_kernel(
        const float* __restrict__ in,       // (bs*64, 845)
        const float* __restrict__ top_out,  // (bs,) float(index)
        const float* __restrict__ fc_w,     // (45, 63)
        const float* __restrict__ fc_b,     // (45,)
        float* __restrict__ out3)           // (bs/5, 45)
{
    const int clip = blockIdx.x;
    const int tid = threadIdx.x;
    __shared__ float avg[NCH3];

    if (tid < NCH3) {
        float s = 0.0f;
        for (int seg = 0; seg < NUM_SEG; ++seg) {
            const int b = clip * NUM_SEG + seg;
            const int t = (int)top_out[b];
            const int ij = t / 5;
            const int d  = t - ij * 5;
            float v = in[(b * NCHIN + tid) * SPAN + d * PLANE + ij];
            if (tid < 3) v = sigmoidf_(v);   // joint 0 sigmoid
            s += v;
        }
        avg[tid] = s * (1.0f / NUM_SEG);
    }
    __syncthreads();
    if (tid < NUM_CLASS) {
        float acc = fc_b[tid];
        #pragma unroll
        for (int k = 0; k < NCH3; ++k) acc += avg[k] * fc_w[tid * NCH3 + k];
        out3[clip * NUM_CLASS + tid] = acc;
    }
}

extern "C" void kernel_launch(void* const* d_in, const int* in_sizes, int n_in,
                              void* d_out, int out_size, void* d_ws, size_t ws_size,
                              hipStream_t stream) {
    const float* base_out = (const float*)d_in[0];
    const float* fc_w     = (const float*)d_in[1];
    const float* fc_b     = (const float*)d_in[2];

    const int bs = in_sizes[0] / (NCHIN * SPAN);   // 2560
    const int clips = bs / NUM_SEG;                // 512

    float* uvd_out = (float*)d_out;                        // bs*63*845
    float* top_out = uvd_out + (size_t)bs * NCH3 * SPAN;   // bs
    float* out3    = top_out + bs;                         // clips*45

    permute_argmax_kernel<<<bs * 16, 256, 0, stream>>>(base_out, uvd_out, top_out);
    fc_consensus_kernel<<<clips, 64, 0, stream>>>(base_out, top_out, fc_w, fc_b, out3);
}